// Round 17
// baseline (76.863 us; speedup 1.0000x reference)
//
#include <hip/hip_runtime.h>

#define D 128       // D_IN == D_OUT == 128
#define CB 256      // nodes per coarse bucket
#define CB_SHIFT 8
#define NB_MAX 512
#define CAP 4096    // slack slots per bucket (requires E <= nb*CAP/2 for safety)

typedef __attribute__((ext_vector_type(8))) short short8;
typedef __attribute__((ext_vector_type(4))) float f32x4;

__device__ inline ushort f2bf(float f) {   // fp32 -> bf16 RNE (scalar)
    uint u = __float_as_uint(f);
    uint r = (u + 0x7FFFu + ((u >> 16) & 1u)) >> 16;
    return (ushort)r;
}

__device__ inline uint cvtpk(float lo, float hi) {  // packed 2x fp32->bf16 RNE
    uint r;
    asm("v_cvt_pk_bf16_f32 %0, %1, %2" : "=v"(r) : "v"(lo), "v"(hi));
    return r;
}

// ---------------- init: zero bucket counters + tile counter + W^T bf16 convert ----------------

__global__ __launch_bounds__(256) void init_kernel(int* __restrict__ cnt,
                                                   int* __restrict__ tilectr,
                                                   const float* __restrict__ W,
                                                   ushort* __restrict__ wT) {
    const int t = threadIdx.x;
    if (blockIdx.x == 0) {
        cnt[t] = 0; cnt[t + 256] = 0;
        if (t == 0) *tilectr = 0;
    }
    const int gt = blockIdx.x * 256 + t;
    if (gt < D * D) { int r = gt >> 7, c = gt & 127; wT[c * D + r] = f2bf(W[gt]); }
}

// ---------------- utility (fallback only) ----------------

__global__ void zero_f4_kernel(float4* __restrict__ out, int n4) {
    int i = blockIdx.x * blockDim.x + threadIdx.x;
    int stride = gridDim.x * blockDim.x;
    float4 z = make_float4(0.f, 0.f, 0.f, 0.f);
    for (; i < n4; i += stride) out[i] = z;
}

// ---------------- fused kernel: partition (blocks < npart) then ALL blocks share gemm tile pool ----
// partition: fixed per-bucket slack regions (b*CAP), zero-init cnt[] cursors.
// GEMM: B in LDS (staged once, one barrier), A direct global->reg, dynamic tile counter.

__global__ __launch_bounds__(512) void gemm_part(const float* __restrict__ embeds,
                                                 const ushort* __restrict__ wT,
                                                 ushort* __restrict__ support, int N,
                                                 const int* __restrict__ dst,
                                                 const int* __restrict__ srcp,
                                                 const float* __restrict__ vals,
                                                 int* __restrict__ cnt,
                                                 int* __restrict__ tilectr,
                                                 int2* __restrict__ pay1, int E, int npart) {
    __shared__ ushort bLds[D * D];     // 32 KB, XOR-swizzled rows (W^T: [n][k])
    __shared__ int phist[NB_MAX];
    __shared__ int pbase[NB_MAX];
    __shared__ int tileSh;
    const int t = threadIdx.x;         // 0..511

    if ((int)blockIdx.x < npart) {
        // ================= partition phase (then fall through to gemm pool) =================
        const int ntile = (E + 2047) >> 11;
        for (int tile = blockIdx.x; tile < ntile; tile += npart) {
            const int e0 = tile << 11;
            if (t < NB_MAX) phist[t] = 0;
            __syncthreads();

            int bk[4], rk[4];
            #pragma unroll
            for (int j = 0; j < 4; ++j) {
                int e = e0 + j * 512 + t;
                bk[j] = -1;
                if (e < E) {
                    bk[j] = dst[e] >> CB_SHIFT;
                    rk[j] = atomicAdd(&phist[bk[j]], 1);
                }
            }
            __syncthreads();

            if (t < NB_MAX)
                pbase[t] = phist[t] ? (t * CAP + atomicAdd(&cnt[t], phist[t])) : 0;
            __syncthreads();

            #pragma unroll
            for (int j = 0; j < 4; ++j) {
                int e = e0 + j * 512 + t;
                if (e >= E) continue;
                int d = dst[e];
                int pos = pbase[bk[j]] + rk[j];
                if (pos < (bk[j] + 1) * CAP) {   // slack clamp (never hit for uniform dst)
                    int key = ((d & (CB - 1)) << 17) | srcp[e];
                    pay1[pos] = make_int2(key, __float_as_int(vals[e]));
                }
            }
            __syncthreads();
        }
        // fall through: join the gemm tile pool
    }

    // ================= GEMM phase (all blocks; dynamic tile pool) =================
    const int w = t >> 6;              // wave 0..7
    const int l = t & 63;
    const int kgrp = l >> 4;           // 0..3
    const int lan15 = l & 15;

    // stage W^T once: 2048 x 16B chunks / 512 threads
    #pragma unroll
    for (int c = 0; c < 4; ++c) {
        int chunk = c * 512 + t;
        int byteoff = chunk * 16;
        int n = byteoff >> 8;
        int dstoff = byteoff ^ ((n & 7) << 4);
        *(float4*)((char*)bLds + dstoff) = *(const float4*)((const char*)wT + byteoff);
    }

    const int ntiles = (N + 127) >> 7;

    for (;;) {
        __syncthreads();               // bLds ready (iter 0) / tileSh consumed (iter k)
        if (t == 0) tileSh = atomicAdd(tilectr, 1);
        __syncthreads();
        const int tile = tileSh;
        if (tile >= ntiles) return;

        const int row0 = tile << 7;
        const int grow = row0 + w * 16 + lan15;    // this lane's A row
        const bool valid = grow < N;
        const float* arow = embeds + (size_t)grow * D + kgrp * 8;

        float4 pf[8];
        if (valid) {
            #pragma unroll
            for (int ks = 0; ks < 4; ++ks) {
                pf[2 * ks]     = *(const float4*)(arow + ks * 32);
                pf[2 * ks + 1] = *(const float4*)(arow + ks * 32 + 4);
            }
        } else {
            #pragma unroll
            for (int j = 0; j < 8; ++j) pf[j] = make_float4(0.f, 0.f, 0.f, 0.f);
        }

        f32x4 acc[8];
        #pragma unroll
        for (int ct = 0; ct < 8; ++ct) acc[ct] = (f32x4)0.0f;

        #pragma unroll
        for (int ks = 0; ks < 4; ++ks) {
            union { uint4 u; short8 s; } cv;
            const float4 f0 = pf[2 * ks], f1 = pf[2 * ks + 1];
            cv.u.x = cvtpk(f0.x, f0.y);
            cv.u.y = cvtpk(f0.z, f0.w);
            cv.u.z = cvtpk(f1.x, f1.y);
            cv.u.w = cvtpk(f1.z, f1.w);
            const short8 af = cv.s;

            const int kbyte = ks * 64 + kgrp * 16;
            #pragma unroll
            for (int ct = 0; ct < 8; ++ct) {
                const int n = ct * 16 + lan15;
                const int boff = (n * 256 + kbyte) ^ ((n & 7) << 4);
                short8 bfr = *(const short8*)((const char*)bLds + boff);
                acc[ct] = __builtin_amdgcn_mfma_f32_16x16x32_bf16(af, bfr, acc[ct], 0, 0, 0);
            }
        }

        #pragma unroll
        for (int r = 0; r < 4; ++r) {
            const int orow = row0 + w * 16 + kgrp * 4 + r;
            if (orow < N) {
                ushort* srow = &support[(size_t)orow * D + lan15];
                #pragma unroll
                for (int cp = 0; cp < 4; ++cp) {
                    uint u = cvtpk(acc[2 * cp][r], acc[2 * cp + 1][r]);
                    srow[(2 * cp) * 16] = (ushort)u;
                    srow[(2 * cp + 1) * 16] = (ushort)(u >> 16);
                }
            }
        }
    }
}

// ---------------- finefill2: per-bucket LDS hist+scan+place; writes per-node {beg,end} ----------------

__global__ __launch_bounds__(256) void finefill2(const int2* __restrict__ pay1,
                                                 const int* __restrict__ cnt,
                                                 int2* __restrict__ ranges,
                                                 int2* __restrict__ pay,
                                                 int N, int nb) {
    __shared__ int lcnt[CB];   // thread t owns node t of the bucket
    __shared__ int bs[CB];
    __shared__ int lofs[CB];
    const int t = threadIdx.x;

    for (int b = blockIdx.x; b < nb; b += gridDim.x) {
        const int beg = b * CAP;
        const int end = beg + min(cnt[b], CAP);
        const int d0 = b << CB_SHIFT;

        lcnt[t] = 0;
        __syncthreads();
        for (int i = beg + t; i < end; i += 256)
            atomicAdd(&lcnt[((unsigned)pay1[i].x) >> 17], 1);
        __syncthreads();

        const int c = lcnt[t];
        bs[t] = c;
        __syncthreads();
        for (int off = 1; off < 256; off <<= 1) {
            int x = (t >= off) ? bs[t - off] : 0;
            __syncthreads();
            bs[t] += x;
            __syncthreads();
        }
        const int run = bs[t] - c + beg;   // exclusive + bucket base
        if (d0 + t < N) ranges[d0 + t] = make_int2(run, run + c);
        lofs[t] = run;
        __syncthreads();

        for (int i = beg + t; i < end; i += 256) {
            int2 p = pay1[i];
            int dl = ((unsigned)p.x) >> 17;
            int pos = atomicAdd(&lofs[dl], 1);
            pay[pos] = make_int2(p.x & 0x1FFFF, p.y);
        }
        __syncthreads();
    }
}

// ---------------- gather: one 16-lane group per dst node ----------------

#define EDGE_MAC(P, M)                                          \
    do {                                                        \
        const float v_ = __int_as_float((P).y);                 \
        acc[0] += v_ * __uint_as_float(((M).x & 0xFFFFu) << 16);\
        acc[1] += v_ * __uint_as_float((M).x & 0xFFFF0000u);    \
        acc[2] += v_ * __uint_as_float(((M).y & 0xFFFFu) << 16);\
        acc[3] += v_ * __uint_as_float((M).y & 0xFFFF0000u);    \
        acc[4] += v_ * __uint_as_float(((M).z & 0xFFFFu) << 16);\
        acc[5] += v_ * __uint_as_float((M).z & 0xFFFF0000u);    \
        acc[6] += v_ * __uint_as_float(((M).w & 0xFFFFu) << 16);\
        acc[7] += v_ * __uint_as_float((M).w & 0xFFFF0000u);    \
    } while (0)

__global__ __launch_bounds__(256, 8) void gather_kernel(const ushort* __restrict__ support,
                                                        const int2* __restrict__ ranges,
                                                        const int2* __restrict__ pay,
                                                        float* __restrict__ out, int N) {
    const int gid = (blockIdx.x * 256 + threadIdx.x) >> 4;   // group id = node id
    const int sl = threadIdx.x & 15;                         // cols sl*8 .. sl*8+7
    if (gid >= N) return;

    const int2 rg = ranges[gid];
    const int beg = rg.x;
    const int end = rg.y;

    float acc[8];
    #pragma unroll
    for (int j = 0; j < 8; ++j) acc[j] = 0.f;

    int i = beg;
    for (; i + 3 < end; i += 4) {   // 4 edges in flight per group
        const int2 p0 = pay[i], p1 = pay[i + 1], p2 = pay[i + 2], p3 = pay[i + 3];
        const uint4 m0 = *(const uint4*)&support[(size_t)p0.x * D + sl * 8];
        const uint4 m1 = *(const uint4*)&support[(size_t)p1.x * D + sl * 8];
        const uint4 m2 = *(const uint4*)&support[(size_t)p2.x * D + sl * 8];
        const uint4 m3 = *(const uint4*)&support[(size_t)p3.x * D + sl * 8];
        EDGE_MAC(p0, m0); EDGE_MAC(p1, m1); EDGE_MAC(p2, m2); EDGE_MAC(p3, m3);
    }
    for (; i + 1 < end; i += 2) {
        const int2 p0 = pay[i], p1 = pay[i + 1];
        const uint4 m0 = *(const uint4*)&support[(size_t)p0.x * D + sl * 8];
        const uint4 m1 = *(const uint4*)&support[(size_t)p1.x * D + sl * 8];
        EDGE_MAC(p0, m0); EDGE_MAC(p1, m1);
    }
    if (i < end) {
        const int2 p0 = pay[i];
        const uint4 m0 = *(const uint4*)&support[(size_t)p0.x * D + sl * 8];
        EDGE_MAC(p0, m0);
    }

    float* o = &out[(size_t)gid * D + sl * 8];
    *(float4*)o       = make_float4(acc[0], acc[1], acc[2], acc[3]);
    *(float4*)(o + 4) = make_float4(acc[4], acc[5], acc[6], acc[7]);
}

// ---------------- fallback: atomic scatter (if path constraints unmet) ----------------

__global__ __launch_bounds__(256) void scatter_kernel(const ushort* __restrict__ support,
                                                      const int* __restrict__ dst,
                                                      const int* __restrict__ src,
                                                      const float* __restrict__ vals,
                                                      float* __restrict__ out, int E) {
    const long long tid = (long long)blockIdx.x * blockDim.x + threadIdx.x;
    const int e = (int)(tid >> 6);
    if (e >= E) return;
    const int c = ((int)tid & 63) * 2;

    const int s = src[e];
    const int d = dst[e];
    const float v = vals[e];

    const uint m = *(const uint*)&support[(size_t)s * D + c];
    const float mx = __uint_as_float((m & 0xFFFFu) << 16);
    const float my = __uint_as_float(m & 0xFFFF0000u);
    atomicAdd(&out[(size_t)d * D + c + 0], v * mx);
    atomicAdd(&out[(size_t)d * D + c + 1], v * my);
}

// ---------------- launch ----------------

static inline char* align256(char* p) {
    return (char*)(((uintptr_t)p + 255) & ~(uintptr_t)255);
}

extern "C" void kernel_launch(void* const* d_in, const int* in_sizes, int n_in,
                              void* d_out, int out_size, void* d_ws, size_t ws_size,
                              hipStream_t stream) {
    const float* embeds = (const float*)d_in[0];
    const float* W      = (const float*)d_in[1];
    const int*   eidx   = (const int*)d_in[2];
    const float* vals   = (const float*)d_in[3];

    const int N = in_sizes[0] / D;   // 100000
    const int E = in_sizes[3];       // 625000
    const int* dstp = eidx;          // edge_index[0]
    const int* srcp = eidx + E;      // edge_index[1]

    float* out = (float*)d_out;

    const int nb = (N + CB - 1) / CB;   // 391 coarse buckets

    // workspace layout (256B-aligned chunks)
    char* p = (char*)d_ws;
    ushort* support = (ushort*)p;  p = align256(p + (size_t)N * D * 2);       // 25.6 MB bf16
    ushort* wT      = (ushort*)p;  p = align256(p + (size_t)D * D * 2);       // 32 KB
    int2* ranges    = (int2*)p;    p = align256(p + (size_t)N * 8);           // 0.8 MB
    int* cnt        = (int*)p;     p = align256(p + NB_MAX * 4);
    int* tilectr    = (int*)p;     p = align256(p + 256);
    int2* pay       = (int2*)p;    p = align256(p + (size_t)nb * CAP * 8);    // 12.8 MB
    int2* pay1      = (int2*)p;    p = align256(p + (size_t)nb * CAP * 8);    // 12.8 MB
    const size_t needed = (size_t)(p - (char*)d_ws);

    const bool two_level = (N <= (1 << 17)) && (nb <= NB_MAX) &&
                           ((long long)E * 2 <= (long long)nb * CAP) &&   // mean <= CAP/2
                           (ws_size >= needed);

    if (two_level) {
        init_kernel<<<64, 256, 0, stream>>>(cnt, tilectr, W, wT);

        // partition (blocks [0,npart)) + gemm pool (all blocks, dynamic tiles)
        const int ntile = (E + 2047) / 2048;
        const int npart = ntile < 512 ? ntile : 512;
        gemm_part<<<npart + 512, 512, 0, stream>>>(embeds, wT, support, N,
                                                   dstp, srcp, vals, cnt, tilectr,
                                                   pay1, E, npart);

        finefill2<<<nb, 256, 0, stream>>>(pay1, cnt, ranges, pay, N, nb);
        gather_kernel<<<(N * 16 + 255) / 256, 256, 0, stream>>>(support, ranges, pay, out, N);
    } else {
        init_kernel<<<64, 256, 0, stream>>>(cnt, tilectr, W, wT);
        gemm_part<<<512, 512, 0, stream>>>(embeds, wT, support, N,
                                           dstp, srcp, vals, cnt, tilectr, pay1, E, 0);
        zero_f4_kernel<<<2048, 256, 0, stream>>>((float4*)out, out_size / 4);
        const long long nthreads = (long long)E * 64;
        const int blocks = (int)((nthreads + 255) / 256);
        scatter_kernel<<<blocks, 256, 0, stream>>>(support, dstp, srcp, vals, out, E);
    }
}

// Round 18
// 74.312 us; speedup vs baseline: 1.0343x; 1.0343x over previous
//
#include <hip/hip_runtime.h>

#define D 128       // D_IN == D_OUT == 128
#define CB 256      // nodes per coarse bucket
#define CB_SHIFT 8
#define NB_MAX 512
#define CAP 4096    // slack slots per bucket (requires E <= nb*CAP/2 for safety)

typedef __attribute__((ext_vector_type(8))) short short8;
typedef __attribute__((ext_vector_type(4))) float f32x4;

__device__ inline ushort f2bf(float f) {   // fp32 -> bf16 RNE (scalar)
    uint u = __float_as_uint(f);
    uint r = (u + 0x7FFFu + ((u >> 16) & 1u)) >> 16;
    return (ushort)r;
}

__device__ inline uint cvtpk(float lo, float hi) {  // packed 2x fp32->bf16 RNE
    uint r;
    asm("v_cvt_pk_bf16_f32 %0, %1, %2" : "=v"(r) : "v"(lo), "v"(hi));
    return r;
}

// ---------------- init: zero bucket counters + W^T bf16 convert (one tiny launch) ----------------

__global__ __launch_bounds__(256) void init_kernel(int* __restrict__ cnt,
                                                   const float* __restrict__ W,
                                                   ushort* __restrict__ wT) {
    const int t = threadIdx.x;
    if (blockIdx.x == 0) { cnt[t] = 0; cnt[t + 256] = 0; }
    const int gt = blockIdx.x * 256 + t;
    if (gt < D * D) { int r = gt >> 7, c = gt & 127; wT[c * D + r] = f2bf(W[gt]); }
}

// ---------------- utility (fallback only) ----------------

__global__ void zero_f4_kernel(float4* __restrict__ out, int n4) {
    int i = blockIdx.x * blockDim.x + threadIdx.x;
    int stride = gridDim.x * blockDim.x;
    float4 z = make_float4(0.f, 0.f, 0.f, 0.f);
    for (; i < n4; i += stride) out[i] = z;
}

// ---------------- fused kernel: partition (blocks < npart) || GEMM (blocks >= npart) ----------------
// partition: fixed per-bucket slack regions (b*CAP), zero-init cnt[] cursors -> no hist/scan stage.
// GEMM: B in LDS (staged once, one barrier), A loaded direct global->reg. No barriers in tile loop.

__global__ __launch_bounds__(512) void gemm_part(const float* __restrict__ embeds,
                                                 const ushort* __restrict__ wT,
                                                 ushort* __restrict__ support, int N,
                                                 const int* __restrict__ dst,
                                                 const int* __restrict__ srcp,
                                                 const float* __restrict__ vals,
                                                 int* __restrict__ cnt,
                                                 int2* __restrict__ pay1, int E, int npart) {
    __shared__ ushort bLds[D * D];     // 32 KB, XOR-swizzled rows (W^T: [n][k])
    __shared__ int phist[NB_MAX];
    __shared__ int pbase[NB_MAX];
    const int t = threadIdx.x;         // 0..511

    if ((int)blockIdx.x < npart) {
        // ================= partition path =================
        const int ntile = (E + 2047) >> 11;
        for (int tile = blockIdx.x; tile < ntile; tile += npart) {
            const int e0 = tile << 11;
            if (t < NB_MAX) phist[t] = 0;
            __syncthreads();

            int bk[4], rk[4];
            #pragma unroll
            for (int j = 0; j < 4; ++j) {
                int e = e0 + j * 512 + t;
                bk[j] = -1;
                if (e < E) {
                    bk[j] = dst[e] >> CB_SHIFT;
                    rk[j] = atomicAdd(&phist[bk[j]], 1);
                }
            }
            __syncthreads();

            if (t < NB_MAX)
                pbase[t] = phist[t] ? (t * CAP + atomicAdd(&cnt[t], phist[t])) : 0;
            __syncthreads();

            #pragma unroll
            for (int j = 0; j < 4; ++j) {
                int e = e0 + j * 512 + t;
                if (e >= E) continue;
                int d = dst[e];
                int pos = pbase[bk[j]] + rk[j];
                if (pos < (bk[j] + 1) * CAP) {   // slack clamp (never hit for uniform dst)
                    int key = ((d & (CB - 1)) << 17) | srcp[e];
                    pay1[pos] = make_int2(key, __float_as_int(vals[e]));
                }
            }
            __syncthreads();
        }
        return;
    }

    // ================= GEMM path =================
    const int gbid = blockIdx.x - npart;
    const int ngemm = gridDim.x - npart;
    const int w = t >> 6;              // wave 0..7
    const int l = t & 63;
    const int kgrp = l >> 4;           // 0..3
    const int lan15 = l & 15;

    // stage W^T once: 2048 x 16B chunks / 512 threads
    #pragma unroll
    for (int c = 0; c < 4; ++c) {
        int chunk = c * 512 + t;
        int byteoff = chunk * 16;
        int n = byteoff >> 8;
        int dstoff = byteoff ^ ((n & 7) << 4);
        *(float4*)((char*)bLds + dstoff) = *(const float4*)((const char*)wT + byteoff);
    }
    __syncthreads();   // the ONLY barrier on the GEMM path

    const int ntiles = (N + 127) >> 7;

    for (int tile = gbid; tile < ntiles; tile += ngemm) {
        const int row0 = tile << 7;
        const int grow = row0 + w * 16 + lan15;    // this lane's A row
        const bool valid = grow < N;
        const float* arow = embeds + (size_t)grow * D + kgrp * 8;

        float4 pf[8];
        if (valid) {
            #pragma unroll
            for (int ks = 0; ks < 4; ++ks) {
                pf[2 * ks]     = *(const float4*)(arow + ks * 32);
                pf[2 * ks + 1] = *(const float4*)(arow + ks * 32 + 4);
            }
        } else {
            #pragma unroll
            for (int j = 0; j < 8; ++j) pf[j] = make_float4(0.f, 0.f, 0.f, 0.f);
        }

        f32x4 acc[8];
        #pragma unroll
        for (int ct = 0; ct < 8; ++ct) acc[ct] = (f32x4)0.0f;

        #pragma unroll
        for (int ks = 0; ks < 4; ++ks) {
            union { uint4 u; short8 s; } cv;
            const float4 f0 = pf[2 * ks], f1 = pf[2 * ks + 1];
            cv.u.x = cvtpk(f0.x, f0.y);
            cv.u.y = cvtpk(f0.z, f0.w);
            cv.u.z = cvtpk(f1.x, f1.y);
            cv.u.w = cvtpk(f1.z, f1.w);
            const short8 af = cv.s;

            const int kbyte = ks * 64 + kgrp * 16;
            #pragma unroll
            for (int ct = 0; ct < 8; ++ct) {
                const int n = ct * 16 + lan15;
                const int boff = (n * 256 + kbyte) ^ ((n & 7) << 4);
                short8 bfr = *(const short8*)((const char*)bLds + boff);
                acc[ct] = __builtin_amdgcn_mfma_f32_16x16x32_bf16(af, bfr, acc[ct], 0, 0, 0);
            }
        }

        #pragma unroll
        for (int r = 0; r < 4; ++r) {
            const int orow = row0 + w * 16 + kgrp * 4 + r;
            if (orow < N) {
                ushort* srow = &support[(size_t)orow * D + lan15];
                #pragma unroll
                for (int cp = 0; cp < 4; ++cp) {
                    uint u = cvtpk(acc[2 * cp][r], acc[2 * cp + 1][r]);
                    srow[(2 * cp) * 16] = (ushort)u;
                    srow[(2 * cp + 1) * 16] = (ushort)(u >> 16);
                }
            }
        }
    }
}

// ---------------- finefill2: per-bucket LDS hist+scan+place; writes per-node {beg,end} ----------------

__global__ __launch_bounds__(256) void finefill2(const int2* __restrict__ pay1,
                                                 const int* __restrict__ cnt,
                                                 int2* __restrict__ ranges,
                                                 int2* __restrict__ pay,
                                                 int N, int nb) {
    __shared__ int lcnt[CB];   // thread t owns node t of the bucket
    __shared__ int bs[CB];
    __shared__ int lofs[CB];
    const int t = threadIdx.x;

    for (int b = blockIdx.x; b < nb; b += gridDim.x) {
        const int beg = b * CAP;
        const int end = beg + min(cnt[b], CAP);
        const int d0 = b << CB_SHIFT;

        lcnt[t] = 0;
        __syncthreads();
        for (int i = beg + t; i < end; i += 256)
            atomicAdd(&lcnt[((unsigned)pay1[i].x) >> 17], 1);
        __syncthreads();

        const int c = lcnt[t];
        bs[t] = c;
        __syncthreads();
        for (int off = 1; off < 256; off <<= 1) {
            int x = (t >= off) ? bs[t - off] : 0;
            __syncthreads();
            bs[t] += x;
            __syncthreads();
        }
        const int run = bs[t] - c + beg;   // exclusive + bucket base
        if (d0 + t < N) ranges[d0 + t] = make_int2(run, run + c);
        lofs[t] = run;
        __syncthreads();

        for (int i = beg + t; i < end; i += 256) {
            int2 p = pay1[i];
            int dl = ((unsigned)p.x) >> 17;
            int pos = atomicAdd(&lofs[dl], 1);
            pay[pos] = make_int2(p.x & 0x1FFFF, p.y);
        }
        __syncthreads();
    }
}

// ---------------- gather: one 16-lane group per dst node ----------------

#define EDGE_MAC(P, M)                                          \
    do {                                                        \
        const float v_ = __int_as_float((P).y);                 \
        acc[0] += v_ * __uint_as_float(((M).x & 0xFFFFu) << 16);\
        acc[1] += v_ * __uint_as_float((M).x & 0xFFFF0000u);    \
        acc[2] += v_ * __uint_as_float(((M).y & 0xFFFFu) << 16);\
        acc[3] += v_ * __uint_as_float((M).y & 0xFFFF0000u);    \
        acc[4] += v_ * __uint_as_float(((M).z & 0xFFFFu) << 16);\
        acc[5] += v_ * __uint_as_float((M).z & 0xFFFF0000u);    \
        acc[6] += v_ * __uint_as_float(((M).w & 0xFFFFu) << 16);\
        acc[7] += v_ * __uint_as_float((M).w & 0xFFFF0000u);    \
    } while (0)

__global__ __launch_bounds__(256, 8) void gather_kernel(const ushort* __restrict__ support,
                                                        const int2* __restrict__ ranges,
                                                        const int2* __restrict__ pay,
                                                        float* __restrict__ out, int N) {
    const int gid = (blockIdx.x * 256 + threadIdx.x) >> 4;   // group id = node id
    const int sl = threadIdx.x & 15;                         // cols sl*8 .. sl*8+7
    if (gid >= N) return;

    const int2 rg = ranges[gid];
    const int beg = rg.x;
    const int end = rg.y;

    float acc[8];
    #pragma unroll
    for (int j = 0; j < 8; ++j) acc[j] = 0.f;

    int i = beg;
    for (; i + 3 < end; i += 4) {   // 4 edges in flight per group
        const int2 p0 = pay[i], p1 = pay[i + 1], p2 = pay[i + 2], p3 = pay[i + 3];
        const uint4 m0 = *(const uint4*)&support[(size_t)p0.x * D + sl * 8];
        const uint4 m1 = *(const uint4*)&support[(size_t)p1.x * D + sl * 8];
        const uint4 m2 = *(const uint4*)&support[(size_t)p2.x * D + sl * 8];
        const uint4 m3 = *(const uint4*)&support[(size_t)p3.x * D + sl * 8];
        EDGE_MAC(p0, m0); EDGE_MAC(p1, m1); EDGE_MAC(p2, m2); EDGE_MAC(p3, m3);
    }
    for (; i + 1 < end; i += 2) {
        const int2 p0 = pay[i], p1 = pay[i + 1];
        const uint4 m0 = *(const uint4*)&support[(size_t)p0.x * D + sl * 8];
        const uint4 m1 = *(const uint4*)&support[(size_t)p1.x * D + sl * 8];
        EDGE_MAC(p0, m0); EDGE_MAC(p1, m1);
    }
    if (i < end) {
        const int2 p0 = pay[i];
        const uint4 m0 = *(const uint4*)&support[(size_t)p0.x * D + sl * 8];
        EDGE_MAC(p0, m0);
    }

    float* o = &out[(size_t)gid * D + sl * 8];
    *(float4*)o       = make_float4(acc[0], acc[1], acc[2], acc[3]);
    *(float4*)(o + 4) = make_float4(acc[4], acc[5], acc[6], acc[7]);
}

// ---------------- fallback: atomic scatter (if path constraints unmet) ----------------

__global__ __launch_bounds__(256) void scatter_kernel(const ushort* __restrict__ support,
                                                      const int* __restrict__ dst,
                                                      const int* __restrict__ src,
                                                      const float* __restrict__ vals,
                                                      float* __restrict__ out, int E) {
    const long long tid = (long long)blockIdx.x * blockDim.x + threadIdx.x;
    const int e = (int)(tid >> 6);
    if (e >= E) return;
    const int c = ((int)tid & 63) * 2;

    const int s = src[e];
    const int d = dst[e];
    const float v = vals[e];

    const uint m = *(const uint*)&support[(size_t)s * D + c];
    const float mx = __uint_as_float((m & 0xFFFFu) << 16);
    const float my = __uint_as_float(m & 0xFFFF0000u);
    atomicAdd(&out[(size_t)d * D + c + 0], v * mx);
    atomicAdd(&out[(size_t)d * D + c + 1], v * my);
}

// ---------------- launch ----------------

static inline char* align256(char* p) {
    return (char*)(((uintptr_t)p + 255) & ~(uintptr_t)255);
}

extern "C" void kernel_launch(void* const* d_in, const int* in_sizes, int n_in,
                              void* d_out, int out_size, void* d_ws, size_t ws_size,
                              hipStream_t stream) {
    const float* embeds = (const float*)d_in[0];
    const float* W      = (const float*)d_in[1];
    const int*   eidx   = (const int*)d_in[2];
    const float* vals   = (const float*)d_in[3];

    const int N = in_sizes[0] / D;   // 100000
    const int E = in_sizes[3];       // 625000
    const int* dstp = eidx;          // edge_index[0]
    const int* srcp = eidx + E;      // edge_index[1]

    float* out = (float*)d_out;

    const int nb = (N + CB - 1) / CB;   // 391 coarse buckets

    // workspace layout (256B-aligned chunks)
    char* p = (char*)d_ws;
    ushort* support = (ushort*)p;  p = align256(p + (size_t)N * D * 2);       // 25.6 MB bf16
    ushort* wT      = (ushort*)p;  p = align256(p + (size_t)D * D * 2);       // 32 KB
    int2* ranges    = (int2*)p;    p = align256(p + (size_t)N * 8);           // 0.8 MB
    int* cnt        = (int*)p;     p = align256(p + NB_MAX * 4);
    int2* pay       = (int2*)p;    p = align256(p + (size_t)nb * CAP * 8);    // 12.8 MB
    int2* pay1      = (int2*)p;    p = align256(p + (size_t)nb * CAP * 8);    // 12.8 MB
    const size_t needed = (size_t)(p - (char*)d_ws);

    const bool two_level = (N <= (1 << 17)) && (nb <= NB_MAX) &&
                           ((long long)E * 2 <= (long long)nb * CAP) &&   // mean <= CAP/2
                           (ws_size >= needed);

    if (two_level) {
        init_kernel<<<64, 256, 0, stream>>>(cnt, W, wT);

        // partition (blocks [0,npart)) + gemm (blocks [npart, npart+512))
        const int ntile = (E + 2047) / 2048;
        const int npart = ntile < 512 ? ntile : 512;
        gemm_part<<<npart + 512, 512, 0, stream>>>(embeds, wT, support, N,
                                                   dstp, srcp, vals, cnt, pay1, E, npart);

        finefill2<<<nb, 256, 0, stream>>>(pay1, cnt, ranges, pay, N, nb);
        gather_kernel<<<(N * 16 + 255) / 256, 256, 0, stream>>>(support, ranges, pay, out, N);
    } else {
        init_kernel<<<64, 256, 0, stream>>>(cnt, W, wT);
        gemm_part<<<512, 512, 0, stream>>>(embeds, wT, support, N,
                                           dstp, srcp, vals, cnt, pay1, E, 0);
        zero_f4_kernel<<<2048, 256, 0, stream>>>((float4*)out, out_size / 4);
        const long long nthreads = (long long)E * 64;
        const int blocks = (int)((nthreads + 255) / 256);
        scatter_kernel<<<blocks, 256, 0, stream>>>(support, dstp, srcp, vals, out, E);
    }
}